// Round 1
// baseline (759.355 us; speedup 1.0000x reference)
//
#include <hip/hip_runtime.h>

// Problem constants (from reference):
// x: (B=64, C=2, T=128, H=96, H=96) f32, only channel 0 used
// NSQ=3, blk=32, V=1024; W_ih (3,3,4,1024); W_hh/b_ih/b_hh (3,3,4)
// out: hs (T=128, B=64, 3, 3) f32
#define T_LEN 128
#define B_SZ  64
#define NC    9       // NSQ*NSQ cells
#define H_SZ  96
#define V_SZ  1024
#define MT    8       // (t,b) pairs processed per wave in gates kernel

// ---------------------------------------------------------------------------
// Kernel 1: x_gates[tb][cell][g] = sum_v x[b,0,t, i*32+p, j*32+q] * W_ih[cell][g][v]
// One wave per (cell, chunk-of-8 tb). Weights live in registers (16 float4/lane),
// reused across MT tb pairs -> weight L2 traffic cut 8x.
// Lane v-mapping (per k in 0..3): v = k*256 + lane*4  (p = v>>5, q = v&31)
// ---------------------------------------------------------------------------
__global__ __launch_bounds__(256) void gates_kernel(
    const float* __restrict__ x,
    const float* __restrict__ W_ih,
    float* __restrict__ xg)   // [T*B][NC][4]  (tb = t*64 + b)
{
    const int lane  = threadIdx.x & 63;
    const int wid   = threadIdx.x >> 6;
    const int wave  = blockIdx.x * 4 + wid;      // 0..9215
    const int cell  = wave >> 10;                // 1024 chunks per cell
    const int chunk = wave & 1023;
    const int i = cell / 3, j = cell % 3;

    // Preload this cell's weights into registers: wf[k][g] = W_ih[cell][g][k*256+lane*4 ..]
    float4 wf[4][4];
    const float* wbase = W_ih + (size_t)cell * 4 * V_SZ;
    #pragma unroll
    for (int k = 0; k < 4; ++k) {
        const int v = k * 256 + lane * 4;
        #pragma unroll
        for (int g = 0; g < 4; ++g)
            wf[k][g] = *(const float4*)(wbase + g * V_SZ + v);
    }

    const int p0 = lane >> 3;          // 0..7 : row within 8-row group
    const int q0 = (lane & 7) * 4;     // 0,4,...,28 : col within 32-wide block
    const int colbase = j * 32 + q0;

    const int tb0 = chunk * MT;
    #pragma unroll 2
    for (int m = 0; m < MT; ++m) {
        const int tb = tb0 + m;
        const int t  = tb >> 6;
        const int b  = tb & 63;
        // x[b, 0, t] slab: ((b*2 + 0)*T + t) * 96*96
        const float* slab = x + ((size_t)(b * 2) * T_LEN + t) * (H_SZ * H_SZ);

        float a0 = 0.f, a1 = 0.f, a2 = 0.f, a3 = 0.f;
        #pragma unroll
        for (int k = 0; k < 4; ++k) {
            const int p = k * 8 + p0;
            const float4 xv = *(const float4*)(slab + (i * 32 + p) * H_SZ + colbase);
            a0 = fmaf(xv.x, wf[k][0].x, fmaf(xv.y, wf[k][0].y, fmaf(xv.z, wf[k][0].z, fmaf(xv.w, wf[k][0].w, a0))));
            a1 = fmaf(xv.x, wf[k][1].x, fmaf(xv.y, wf[k][1].y, fmaf(xv.z, wf[k][1].z, fmaf(xv.w, wf[k][1].w, a1))));
            a2 = fmaf(xv.x, wf[k][2].x, fmaf(xv.y, wf[k][2].y, fmaf(xv.z, wf[k][2].z, fmaf(xv.w, wf[k][2].w, a2))));
            a3 = fmaf(xv.x, wf[k][3].x, fmaf(xv.y, wf[k][3].y, fmaf(xv.z, wf[k][3].z, fmaf(xv.w, wf[k][3].w, a3))));
        }

        // Butterfly reduction across the 64-lane wave
        #pragma unroll
        for (int off = 32; off; off >>= 1) {
            a0 += __shfl_xor(a0, off, 64);
            a1 += __shfl_xor(a1, off, 64);
            a2 += __shfl_xor(a2, off, 64);
            a3 += __shfl_xor(a3, off, 64);
        }

        if (lane == 0) {
            float4 r = make_float4(a0, a1, a2, a3);
            *(float4*)(xg + ((size_t)tb * NC + cell) * 4) = r;
        }
    }
}

// ---------------------------------------------------------------------------
// Kernel 2: sequential LSTM scan, one thread per (b, cell). 576 threads total.
// Gate order (i, f, g, o). Biases (b_ih + b_hh) folded here.
// ---------------------------------------------------------------------------
__global__ __launch_bounds__(64) void scan_kernel(
    const float* __restrict__ xg,     // [T][B*NC][4]
    const float* __restrict__ W_hh,   // [NC][4]
    const float* __restrict__ b_ih,   // [NC][4]
    const float* __restrict__ b_hh,   // [NC][4]
    float* __restrict__ out)          // [T][B*NC]
{
    const int tid  = blockIdx.x * 64 + threadIdx.x;   // 0..575  (= b*9 + cell)
    const int cell = tid % 9;

    const float4 wh = *(const float4*)(W_hh + cell * 4);
    const float4 bi = *(const float4*)(b_ih + cell * 4);
    const float4 bh = *(const float4*)(b_hh + cell * 4);
    const float bx = bi.x + bh.x, by = bi.y + bh.y, bz = bi.z + bh.z, bw = bi.w + bh.w;

    const float4* xg4 = (const float4*)xg;

    float h = 0.f, c = 0.f;
    float4 g = xg4[tid];                       // t = 0
    for (int t = 0; t < T_LEN; ++t) {
        const int tn = (t + 1 < T_LEN) ? t + 1 : t;
        const float4 gn = xg4[(size_t)tn * (B_SZ * NC) + tid];   // prefetch next step

        const float gi = g.x + bx + wh.x * h;
        const float gf = g.y + by + wh.y * h;
        const float gz = g.z + bz + wh.z * h;
        const float go = g.w + bw + wh.w * h;

        const float ii = 1.f / (1.f + __expf(-gi));
        const float ff = 1.f / (1.f + __expf(-gf));
        const float gt = tanhf(gz);
        const float oo = 1.f / (1.f + __expf(-go));

        c = ff * c + ii * gt;
        h = oo * tanhf(c);

        out[(size_t)t * (B_SZ * NC) + tid] = h;
        g = gn;
    }
}

extern "C" void kernel_launch(void* const* d_in, const int* in_sizes, int n_in,
                              void* d_out, int out_size, void* d_ws, size_t ws_size,
                              hipStream_t stream) {
    const float* x    = (const float*)d_in[0];
    const float* W_ih = (const float*)d_in[1];
    const float* W_hh = (const float*)d_in[2];
    const float* b_ih = (const float*)d_in[3];
    const float* b_hh = (const float*)d_in[4];
    float* out = (float*)d_out;

    float* xg = (float*)d_ws;   // T*B*NC*4 floats = 1.18 MB

    // Kernel 1: 9216 waves total = 2304 blocks of 256 (4 waves each)
    gates_kernel<<<dim3((NC * (T_LEN * B_SZ / MT)) / 4), dim3(256), 0, stream>>>(x, W_ih, xg);

    // Kernel 2: 576 threads = 9 blocks of 64
    scan_kernel<<<dim3(NC), dim3(64), 0, stream>>>(xg, W_hh, b_ih, b_hh, out);
}

// Round 2
// 733.651 us; speedup vs baseline: 1.0350x; 1.0350x over previous
//
#include <hip/hip_runtime.h>

// x: (B=64, C=2, T=128, H=96, H=96) f32, only channel 0 used
// NSQ=3, blk=32, V=1024; W_ih (3,3,4,1024); W_hh/b_ih/b_hh (3,3,4)
// out: hs (T=128, B=64, 3, 3) f32
#define T_LEN 128
#define B_SZ  64
#define NC    9       // NSQ*NSQ cells
#define H_SZ  96
#define V_SZ  1024
#define MT    8       // (t,b) pairs per wave in gates kernel

// ---------------------------------------------------------------------------
// Kernel 1: x_gates[tb][cell][g] = sum_v x[b,0,t, i*32+p, j*32+q] * W_ih[cell][g][v]
// One wave per (cell, chunk-of-8 tb). Weights in registers (16 float4/lane),
// reused across MT tb pairs. Software-pipelined x loads (1 tb ahead).
// Reduction: 7 shuffles/tb (gate-interleaved fold), 4-lane coalesced store.
// ---------------------------------------------------------------------------
__global__ __launch_bounds__(256) void gates_kernel(
    const float* __restrict__ x,
    const float* __restrict__ W_ih,
    float* __restrict__ xg)   // [T*B][NC][4]  (tb = t*64 + b)
{
    const int lane  = threadIdx.x & 63;
    const int wid   = threadIdx.x >> 6;
    const int wave  = blockIdx.x * 4 + wid;      // 0..9215
    const int cell  = wave >> 10;                // 1024 chunks per cell
    const int chunk = wave & 1023;
    const int i = cell / 3, j = cell % 3;

    // Registers: wf[k][g] = W_ih[cell][g][k*256 + lane*4 .. +3]
    float4 wf[4][4];
    const float* wbase = W_ih + (size_t)cell * 4 * V_SZ;
    #pragma unroll
    for (int k = 0; k < 4; ++k) {
        const int v = k * 256 + lane * 4;
        #pragma unroll
        for (int g = 0; g < 4; ++g)
            wf[k][g] = *(const float4*)(wbase + g * V_SZ + v);
    }

    const int p0 = lane >> 3;          // 0..7
    const int q0 = (lane & 7) * 4;     // 0,4,..,28
    const int rowcol = (i * 32) * H_SZ + j * 32 + q0;

    const int tb0 = chunk * MT;

    // Prologue: load tb0's block
    float4 xv[4];
    {
        const int t = tb0 >> 6, b = tb0 & 63;
        const float* slab = x + ((size_t)(b * 2) * T_LEN + t) * (H_SZ * H_SZ) + rowcol;
        #pragma unroll
        for (int k = 0; k < 4; ++k)
            xv[k] = *(const float4*)(slab + (k * 8 + p0) * H_SZ);
    }

    #pragma unroll
    for (int m = 0; m < MT; ++m) {
        float4 nx[4];
        if (m + 1 < MT) {
            const int tbn = tb0 + m + 1;
            const int t = tbn >> 6, b = tbn & 63;
            const float* slab = x + ((size_t)(b * 2) * T_LEN + t) * (H_SZ * H_SZ) + rowcol;
            #pragma unroll
            for (int k = 0; k < 4; ++k)
                nx[k] = *(const float4*)(slab + (k * 8 + p0) * H_SZ);
        }

        float a0 = 0.f, a1 = 0.f, a2 = 0.f, a3 = 0.f;
        #pragma unroll
        for (int k = 0; k < 4; ++k) {
            const float4 v = xv[k];
            a0 = fmaf(v.x, wf[k][0].x, fmaf(v.y, wf[k][0].y, fmaf(v.z, wf[k][0].z, fmaf(v.w, wf[k][0].w, a0))));
            a1 = fmaf(v.x, wf[k][1].x, fmaf(v.y, wf[k][1].y, fmaf(v.z, wf[k][1].z, fmaf(v.w, wf[k][1].w, a1))));
            a2 = fmaf(v.x, wf[k][2].x, fmaf(v.y, wf[k][2].y, fmaf(v.z, wf[k][2].z, fmaf(v.w, wf[k][2].w, a2))));
            a3 = fmaf(v.x, wf[k][3].x, fmaf(v.y, wf[k][3].y, fmaf(v.z, wf[k][3].z, fmaf(v.w, wf[k][3].w, a3))));
        }

        // Gate-interleaved reduction: 7 shuffles total.
        // Stage 1 (xor 1): fold (a0,a1) and (a2,a3); lane parity picks gate.
        const bool m1 = (lane & 1) != 0;
        float y01 = m1 ? a0 : a1;
        float a01 = (m1 ? a1 : a0) + __shfl_xor(y01, 1, 64);   // gate (lane&1), pairs summed
        float y23 = m1 ? a2 : a3;
        float a23 = (m1 ? a3 : a2) + __shfl_xor(y23, 1, 64);   // gate 2+(lane&1)
        // Stage 2 (xor 2): fold a01/a23; lane bit1 picks gate pair.
        const bool m2 = (lane & 2) != 0;
        float ys = m2 ? a01 : a23;
        float s  = (m2 ? a23 : a01) + __shfl_xor(ys, 2, 64);   // gate (lane&3), quads summed
        // Stages 3-6: plain butterfly.
        s += __shfl_xor(s, 4, 64);
        s += __shfl_xor(s, 8, 64);
        s += __shfl_xor(s, 16, 64);
        s += __shfl_xor(s, 32, 64);

        if (lane < 4)
            xg[((size_t)(tb0 + m) * NC + cell) * 4 + lane] = s;

        #pragma unroll
        for (int k = 0; k < 4; ++k) xv[k] = nx[k];
    }
}

// ---------------------------------------------------------------------------
// Kernel 2: sequential LSTM scan, one thread per (b, cell). 576 threads.
// Fast sigmoid/tanh via v_exp + v_rcp (tolerance is 2e-2; these are ~1e-6).
// ---------------------------------------------------------------------------
__device__ __forceinline__ float fsig(float xx) {
    return __builtin_amdgcn_rcpf(1.f + __expf(-xx));
}
__device__ __forceinline__ float ftanh(float xx) {
    // tanh(x) = 1 - 2/(1 + e^{2x}); exp->inf / ->0 saturate correctly via rcp.
    return fmaf(-2.f, __builtin_amdgcn_rcpf(1.f + __expf(2.f * xx)), 1.f);
}

__global__ __launch_bounds__(64) void scan_kernel(
    const float* __restrict__ xg,     // [T][B*NC][4]
    const float* __restrict__ W_hh,   // [NC][4]
    const float* __restrict__ b_ih,   // [NC][4]
    const float* __restrict__ b_hh,   // [NC][4]
    float* __restrict__ out)          // [T][B*NC]
{
    const int tid  = blockIdx.x * 64 + threadIdx.x;   // 0..575  (= b*9 + cell)
    const int cell = tid % 9;

    const float4 wh = *(const float4*)(W_hh + cell * 4);
    const float4 bi = *(const float4*)(b_ih + cell * 4);
    const float4 bh = *(const float4*)(b_hh + cell * 4);
    const float bx = bi.x + bh.x, by = bi.y + bh.y, bz = bi.z + bh.z, bw = bi.w + bh.w;

    const float4* xg4 = (const float4*)xg;

    float h = 0.f, c = 0.f;
    float4 g = xg4[tid];                       // t = 0
    for (int t = 0; t < T_LEN; ++t) {
        const int tn = (t + 1 < T_LEN) ? t + 1 : t;
        const float4 gn = xg4[(size_t)tn * (B_SZ * NC) + tid];   // prefetch

        const float gi = fmaf(wh.x, h, g.x + bx);
        const float gf = fmaf(wh.y, h, g.y + by);
        const float gz = fmaf(wh.z, h, g.z + bz);
        const float go = fmaf(wh.w, h, g.w + bw);

        const float ii = fsig(gi);
        const float ff = fsig(gf);
        const float gt = ftanh(gz);
        const float oo = fsig(go);

        c = fmaf(ff, c, ii * gt);
        h = oo * ftanh(c);

        out[(size_t)t * (B_SZ * NC) + tid] = h;
        g = gn;
    }
}

extern "C" void kernel_launch(void* const* d_in, const int* in_sizes, int n_in,
                              void* d_out, int out_size, void* d_ws, size_t ws_size,
                              hipStream_t stream) {
    const float* x    = (const float*)d_in[0];
    const float* W_ih = (const float*)d_in[1];
    const float* W_hh = (const float*)d_in[2];
    const float* b_ih = (const float*)d_in[3];
    const float* b_hh = (const float*)d_in[4];
    float* out = (float*)d_out;

    float* xg = (float*)d_ws;   // T*B*NC*4 floats = 1.18 MB

    gates_kernel<<<dim3((NC * (T_LEN * B_SZ / MT)) / 4), dim3(256), 0, stream>>>(x, W_ih, xg);
    scan_kernel<<<dim3(NC), dim3(64), 0, stream>>>(xg, W_hh, b_ih, b_hh, out);
}